// Round 1
// 393.450 us; speedup vs baseline: 1.0263x; 1.0263x over previous
//
#include <hip/hip_runtime.h>
#include <hip/hip_bf16.h>

#define B_    2
#define S_    2048
#define H_    2048
#define NH_   16
#define NKV_  4
#define D_    128
#define WIN_  1024

typedef __attribute__((ext_vector_type(8))) short short8;
typedef __attribute__((ext_vector_type(4))) float f32x4;

__device__ __forceinline__ void gl2lds16(const void* g, void* l) {
  __builtin_amdgcn_global_load_lds(
      (const __attribute__((address_space(1))) void*)g,
      (__attribute__((address_space(3))) void*)l, 16, 0, 0);
}

__device__ __forceinline__ unsigned short f2bf(float x) {
  union { float f; unsigned int u; } v; v.f = x;
  unsigned int r = v.u + 0x7fffu + ((v.u >> 16) & 1u);
  return (unsigned short)(r >> 16);
}
__device__ __forceinline__ float bf2f(unsigned short u) {
  union { unsigned int i; float f; } v; v.i = ((unsigned int)u) << 16; return v.f;
}

// ---------------- fused fp32 -> bf16 convert, all 6 tensors in one launch ----
// TOTAL = 5,767,168 float4 chunks = 22,528 blocks x 256.
#define CVT_TOTAL 5767168L
__global__ __launch_bounds__(256) void convert_all(
    const float* __restrict__ hs, const float* __restrict__ wq,
    const float* __restrict__ wk, const float* __restrict__ wv,
    const float* __restrict__ wg, const float* __restrict__ wo,
    unsigned short* __restrict__ xb, unsigned short* __restrict__ wall,
    unsigned short* __restrict__ wob) {
  long i = (long)blockIdx.x * 256 + threadIdx.x;
  if (i >= CVT_TOTAL) return;
  const float4* src; ushort4* dst;
  if (i < 2097152)      { src = (const float4*)hs + i;                         dst = (ushort4*)xb + i; }
  else if (i < 3145728) { long j = i - 2097152; src = (const float4*)wq + j;   dst = (ushort4*)wall + j; }
  else if (i < 3407872) { long j = i - 3145728; src = (const float4*)wk + j;   dst = (ushort4*)wall + 1048576 + j; }
  else if (i < 3670016) { long j = i - 3407872; src = (const float4*)wv + j;   dst = (ushort4*)wall + 1310720 + j; }
  else if (i < 4718592) { long j = i - 3670016; src = (const float4*)wg + j;   dst = (ushort4*)wall + 1572864 + j; }
  else                  { long j = i - 4718592; src = (const float4*)wo + j;   dst = (ushort4*)wob + j; }
  float4 v = *src;
  ushort4 o; o.x = f2bf(v.x); o.y = f2bf(v.y); o.z = f2bf(v.z); o.w = f2bf(v.w);
  *dst = o;
}

// ---------------- bf16 GEMM: C(MxN) = A(MxK) * B(NxK)^T ----------------
// 128x128 tile, BK=64 (32 K-iters: half the barrier drains of BK=32), 256 thr,
// global_load_lds(16B). Swizzle: physical 16B chunk pc of row r holds logical
// chunk pc^(r&7) (permutation within the 128B row -> global reads stay
// contiguous per row; gl2lds LDS writes stay contiguous). Fragment reads fetch
// physical (kk*4+quad)^(row&7) -> logical kk*4+quad; each 8-lane b128 phase
// covers bank bases {0,4,..,28} = all 32 banks, conflict-free.
template <bool OUT_BF16>
__global__ __launch_bounds__(256) void gemm_bt(
    const unsigned short* __restrict__ A,
    const unsigned short* __restrict__ Bm,
    void* __restrict__ Cv, int M, int N, int K)
{
  __shared__ unsigned short As[128 * 64];
  __shared__ unsigned short Bs[128 * 64];
  const int t = threadIdx.x;
  const int lane = t & 63, wave = t >> 6;
  const int quad = lane >> 4, rl = lane & 15;
  const int bm = blockIdx.x * 128, bn = blockIdx.y * 128;
  const int wm = (wave >> 1) * 64, wn = (wave & 1) * 64;
  const int ldsbase = (t & ~63) * 8;   // wave*512 shorts (1 KiB per wave-instr)

  f32x4 acc[4][4];
#pragma unroll
  for (int i = 0; i < 4; i++)
#pragma unroll
    for (int j = 0; j < 4; j++) acc[i][j] = (f32x4){0.f, 0.f, 0.f, 0.f};

  for (int k0 = 0; k0 < K; k0 += 64) {
#pragma unroll
    for (int i = 0; i < 4; i++) {
      int tt = i * 256 + t;                    // physical 16B-chunk id (0..1023)
      int row = tt >> 3;
      int lc = (tt & 7) ^ (row & 7);           // logical chunk to fetch
      gl2lds16(A + (long)(bm + row) * K + k0 + lc * 8, As + i * 2048 + ldsbase);
      gl2lds16(Bm + (long)(bn + row) * K + k0 + lc * 8, Bs + i * 2048 + ldsbase);
    }
    __syncthreads();
#pragma unroll
    for (int kk = 0; kk < 2; kk++) {
      short8 af[4], bfr[4];
#pragma unroll
      for (int i = 0; i < 4; i++) {
        int row = wm + i * 16 + rl;
        af[i] = *(const short8*)(As + row * 64 + (((kk * 4 + quad) ^ (row & 7)) * 8));
      }
#pragma unroll
      for (int j = 0; j < 4; j++) {
        int row = wn + j * 16 + rl;
        bfr[j] = *(const short8*)(Bs + row * 64 + (((kk * 4 + quad) ^ (row & 7)) * 8));
      }
#pragma unroll
      for (int i = 0; i < 4; i++)
#pragma unroll
        for (int j = 0; j < 4; j++)
          acc[i][j] = __builtin_amdgcn_mfma_f32_16x16x32_bf16(af[i], bfr[j], acc[i][j], 0, 0, 0);
    }
    __syncthreads();
  }
#pragma unroll
  for (int i = 0; i < 4; i++) {
    int row0 = bm + wm + i * 16 + quad * 4;
#pragma unroll
    for (int j = 0; j < 4; j++) {
      int col = bn + wn + j * 16 + rl;
#pragma unroll
      for (int r = 0; r < 4; r++) {
        if (OUT_BF16)
          ((unsigned short*)Cv)[(long)(row0 + r) * N + col] = f2bf(acc[i][j][r]);
        else
          ((float*)Cv)[(long)(row0 + r) * N + col] = acc[i][j][r];
      }
    }
  }
}

// ------- RMSNorm+RoPE pack (blocks 0..20479) + V transpose (blocks 20480+) ---
__global__ __launch_bounds__(256) void pack_and_transpose(
    const unsigned short* __restrict__ qkvg,
    const float* __restrict__ cosb, const float* __restrict__ sinb,
    const float* __restrict__ qw, const float* __restrict__ kw,
    unsigned short* __restrict__ qb, unsigned short* __restrict__ kb,
    unsigned short* __restrict__ vt)
{
  __shared__ unsigned short tile[64][136];
  int t = threadIdx.x;
  if (blockIdx.x >= 20480) {                   // ---- V transpose path ----
    int blk = blockIdx.x - 20480;
    int st = blk & 31, kv = (blk >> 5) & 3, b = blk >> 7;
    int s0 = st * 64;
#pragma unroll
    for (int i = 0; i < 4; i++) {
      int idx = i * 256 + t;
      int r = idx >> 4, c = (idx & 15) * 8;
      short8 v = *(const short8*)(qkvg + (long)(b * S_ + s0 + r) * 5120 + 2560 + kv * 128 + c);
      *(short8*)(&tile[r][c]) = v;
    }
    __syncthreads();
    long vo = (long)(b * NKV_ + kv) * 128;
#pragma unroll
    for (int i = 0; i < 8; i++) {
      int idx = i * 256 + t;
      int d = idx >> 4, sc = idx & 15;
      ushort4 o;
      o.x = tile[sc * 4 + 0][d]; o.y = tile[sc * 4 + 1][d];
      o.z = tile[sc * 4 + 2][d]; o.w = tile[sc * 4 + 3][d];
      *(ushort4*)(vt + (vo + d) * S_ + s0 + sc * 4) = o;
    }
    return;
  }
  // ---- RMSNorm + RoPE path ----
  int lane = t & 63, wave = t >> 6;
  long gw = (long)blockIdx.x * 4 + wave;
  int hu = (int)(gw % 20);
  long bs = gw / 20;
  int b = (int)(bs / S_);
  int s = (int)(bs % S_);
  const unsigned short* row = qkvg + bs * 5120;

  bool isq = hu < 16;
  const unsigned short* base = isq ? (row + hu * 128) : (row + 2048 + (hu - 16) * 128);
  float x1 = bf2f(base[lane]), x2 = bf2f(base[lane + 64]);
  float ss = x1 * x1 + x2 * x2;
#pragma unroll
  for (int m = 1; m < 64; m <<= 1) ss += __shfl_xor(ss, m, 64);
  float inv = rsqrtf(ss * (1.0f / 128.0f) + 1e-5f);
  const float* w = isq ? qw : kw;
  float n1 = x1 * inv * w[lane], n2 = x2 * inv * w[lane + 64];
  const float* cp = cosb + bs * 128;
  const float* sp = sinb + bs * 128;
  float o1 = n1 * cp[lane] - n2 * sp[lane];
  float o2 = n2 * cp[lane + 64] + n1 * sp[lane + 64];
  if (isq) {
    long o = ((long)(b * NH_ + hu) * S_ + s) * 128;
    qb[o + lane] = f2bf(o1); qb[o + lane + 64] = f2bf(o2);
  } else {
    long o = ((long)(b * NKV_ + (hu - 16)) * S_ + s) * 128;
    kb[o + lane] = f2bf(o1); kb[o + lane + 64] = f2bf(o2);
  }
}

// ---------------- flash attention: 1024 blocks x 4 waves, GQA-shared K/V -----
// Block = (qt-desc, b, kv, quarter): 4 waves = 4 heads, each wave does 16 q
// rows (1 mtile). Finer grid (512->1024 blocks) + LDS 43.5KB -> 3 blocks/CU
// resident with 4 avail -> occupancy-bound stalls shrink.
// T13 defer-rescale: skip alpha pass when no row max grows (wave-uniform).
// Ps stride 68 (was 72): P b16 writes land quads on disjoint 8-bank spans.
#define KSTR 136   // 128 + 8 shorts
#define VSTR 72    // 64 + 8 shorts
#define PSTR 68    // 64 + 4 shorts
__global__ __launch_bounds__(256, 3) void attn_kernel(
    const unsigned short* __restrict__ qb,   // [B,NH,S,D]
    const unsigned short* __restrict__ kbuf, // [B,NKV,S,D]
    const unsigned short* __restrict__ vt,   // [B,NKV,D,S]
    const unsigned short* __restrict__ qkvg, // gate at col 3072+
    unsigned short* __restrict__ aout)       // [B,S,NH*D] bf16
{
  __shared__ unsigned short Ks[64 * KSTR];      // (key, d) padded
  __shared__ unsigned short Vs[128 * VSTR];     // (d, key) padded
  __shared__ unsigned short Ps[4][16 * PSTR];   // per-wave P (16 rows x 64)
  int t = threadIdx.x, lane = t & 63, wave = t >> 6;
  int quad = lane >> 4, rl = lane & 15;
  int blk = blockIdx.x;
  int qt = 31 - (blk >> 5);                  // heavy blocks dispatch first
  int qu = blk & 3;
  int kv = (blk >> 2) & 3;
  int b  = (blk >> 4) & 1;
  int h = kv * 4 + wave;
  int q0 = qt * 64 + qu * 16;

  const unsigned short* qhead = qb + (((long)(b * NH_ + h)) * S_) * 128;
  short8 qf[4];
#pragma unroll
  for (int ks = 0; ks < 4; ks++)
    qf[ks] = *(const short8*)(qhead + (long)(q0 + rl) * 128 + ks * 32 + quad * 8);

  f32x4 oacc[8];
#pragma unroll
  for (int j = 0; j < 8; j++) oacc[j] = (f32x4){0.f, 0.f, 0.f, 0.f};
  float m_r[4], l_r[4];
#pragma unroll
  for (int r = 0; r < 4; r++) { m_r[r] = -1e9f; l_r[r] = 0.f; }

  const unsigned short* kbase_p = kbuf + ((long)(b * NKV_ + kv)) * S_ * 128;
  const unsigned short* vbase_p = vt + ((long)(b * NKV_ + kv)) * 128 * S_;
  int t_lo = qt - 16; if (t_lo < 0) t_lo = 0;

  // staging indices: K = 64x16 chunks, V = 128x8 chunks; 1024 each / 256 thr
  int kr[4], kc[4], vr[4], vc[4];
#pragma unroll
  for (int i = 0; i < 4; i++) {
    int idx = i * 256 + t;
    kr[i] = idx >> 4; kc[i] = (idx & 15) * 8;
    vr[i] = idx >> 3; vc[i] = (idx & 7) * 8;
  }

  {
    int kb0 = t_lo * 64;
    short8 kv0[4], vv0[4];
#pragma unroll
    for (int i = 0; i < 4; i++) {
      kv0[i] = *(const short8*)(kbase_p + (long)(kb0 + kr[i]) * 128 + kc[i]);
      vv0[i] = *(const short8*)(vbase_p + (long)vr[i] * S_ + kb0 + vc[i]);
    }
#pragma unroll
    for (int i = 0; i < 4; i++) {
      *(short8*)(Ks + kr[i] * KSTR + kc[i]) = kv0[i];
      *(short8*)(Vs + vr[i] * VSTR + vc[i]) = vv0[i];
    }
  }
  __syncthreads();

  const float scale = 0.08838834764831845f;  // 1/sqrt(128)
  for (int kt = t_lo; kt <= qt; ++kt) {
    int kb0 = kt * 64;
    short8 kpre[4], vpre[4];
    if (kt < qt) {
      int nb0 = kb0 + 64;
#pragma unroll
      for (int i = 0; i < 4; i++) {
        kpre[i] = *(const short8*)(kbase_p + (long)(nb0 + kr[i]) * 128 + kc[i]);
        vpre[i] = *(const short8*)(vbase_p + (long)vr[i] * S_ + nb0 + vc[i]);
      }
    }

    f32x4 sc[4];
    __builtin_amdgcn_s_setprio(1);
#pragma unroll
    for (int nt = 0; nt < 4; nt++) {
      f32x4 c0 = (f32x4){0.f, 0.f, 0.f, 0.f};
#pragma unroll
      for (int ks = 0; ks < 4; ks++) {
        short8 bfrag = *(const short8*)(Ks + (nt * 16 + rl) * KSTR + (ks * 4 + quad) * 8);
        c0 = __builtin_amdgcn_mfma_f32_16x16x32_bf16(qf[ks], bfrag, c0, 0, 0, 0);
      }
      sc[nt] = c0;
    }
    __builtin_amdgcn_s_setprio(0);

#pragma unroll
    for (int nt = 0; nt < 4; nt++)
#pragma unroll
      for (int r = 0; r < 4; r++) {
        int i_row = q0 + quad * 4 + r;
        int j_col = kb0 + nt * 16 + rl;
        bool ok = (j_col <= i_row) && (i_row - j_col < WIN_);
        sc[nt][r] = ok ? sc[nt][r] * scale : -1e9f;
      }

    float mx[4];
#pragma unroll
    for (int r = 0; r < 4; r++) {
      float m0 = fmaxf(fmaxf(sc[0][r], sc[1][r]), fmaxf(sc[2][r], sc[3][r]));
#pragma unroll
      for (int m = 1; m < 16; m <<= 1) m0 = fmaxf(m0, __shfl_xor(m0, m, 64));
      mx[r] = m0;
    }
    // T13 defer-rescale: only pay the alpha pass when some row max grew.
    bool need = (mx[0] > m_r[0]) | (mx[1] > m_r[1]) |
                (mx[2] > m_r[2]) | (mx[3] > m_r[3]);
    if (__any(need)) {
#pragma unroll
      for (int r = 0; r < 4; r++) {
        float newm = fmaxf(m_r[r], mx[r]);
        float alpha = __expf(m_r[r] - newm);
        l_r[r] *= alpha;
#pragma unroll
        for (int j = 0; j < 8; j++) oacc[j][r] *= alpha;
        m_r[r] = newm;
      }
    }
#pragma unroll
    for (int r = 0; r < 4; r++) {
      float p0 = __expf(sc[0][r] - m_r[r]), p1 = __expf(sc[1][r] - m_r[r]);
      float p2 = __expf(sc[2][r] - m_r[r]), p3 = __expf(sc[3][r] - m_r[r]);
      float rs = p0 + p1 + p2 + p3;
#pragma unroll
      for (int m = 1; m < 16; m <<= 1) rs += __shfl_xor(rs, m, 64);
      l_r[r] += rs;
      unsigned short* pw = &Ps[wave][(quad * 4 + r) * PSTR];
      pw[0 * 16 + rl] = f2bf(p0);
      pw[1 * 16 + rl] = f2bf(p1);
      pw[2 * 16 + rl] = f2bf(p2);
      pw[3 * 16 + rl] = f2bf(p3);
    }

    __builtin_amdgcn_s_setprio(1);
#pragma unroll
    for (int ks2 = 0; ks2 < 2; ks2++) {
      short8 af = *(const short8*)(&Ps[wave][rl * PSTR + (ks2 * 4 + quad) * 8]);
#pragma unroll
      for (int j = 0; j < 8; j++) {
        short8 bf2 = *(const short8*)(Vs + (j * 16 + rl) * VSTR + (ks2 * 4 + quad) * 8);
        oacc[j] = __builtin_amdgcn_mfma_f32_16x16x32_bf16(af, bf2, oacc[j], 0, 0, 0);
      }
    }
    __builtin_amdgcn_s_setprio(0);

    if (kt < qt) {
      __syncthreads();
#pragma unroll
      for (int i = 0; i < 4; i++) {
        *(short8*)(Ks + kr[i] * KSTR + kc[i]) = kpre[i];
        *(short8*)(Vs + vr[i] * VSTR + vc[i]) = vpre[i];
      }
      __syncthreads();
    }
  }

#pragma unroll
  for (int r = 0; r < 4; r++) {
    int s_idx = q0 + quad * 4 + r;
    float invl = 1.0f / l_r[r];
    long rowoff = (long)(b * S_ + s_idx);
    const unsigned short* gptr = qkvg + rowoff * 5120 + 3072 + h * 128;
    unsigned short* orow = aout + rowoff * 2048 + h * 128;
#pragma unroll
    for (int j = 0; j < 8; j++) {
      int d = j * 16 + rl;
      float o = oacc[j][r] * invl;
      float g = bf2f(gptr[d]);
      o = o / (1.0f + __expf(-g));
      orow[d] = f2bf(o);
    }
  }
}

extern "C" void kernel_launch(void* const* d_in, const int* in_sizes, int n_in,
                              void* d_out, int out_size, void* d_ws, size_t ws_size,
                              hipStream_t stream) {
  (void)in_sizes; (void)n_in; (void)out_size; (void)ws_size;
  const float* hs   = (const float*)d_in[0];
  const float* cosb = (const float*)d_in[1];
  const float* sinb = (const float*)d_in[2];
  const float* Wq = (const float*)d_in[4];
  const float* Wk = (const float*)d_in[5];
  const float* Wv = (const float*)d_in[6];
  const float* Wo = (const float*)d_in[7];
  const float* Wg = (const float*)d_in[8];
  const float* qw = (const float*)d_in[9];
  const float* kw = (const float*)d_in[10];
  float* out = (float*)d_out;

  char* ws = (char*)d_ws;
  unsigned short* Xb   = (unsigned short*)ws; ws += (size_t)4096 * 2048 * 2;
  unsigned short* Wall = (unsigned short*)ws; ws += (size_t)5120 * 2048 * 2;
  unsigned short* Wob  = (unsigned short*)ws; ws += (size_t)2048 * 2048 * 2;
  unsigned short* qkvg = (unsigned short*)ws; ws += (size_t)4096 * 5120 * 2;
  unsigned short* qb   = (unsigned short*)ws; ws += (size_t)B_ * NH_ * S_ * D_ * 2;
  unsigned short* kbuf = (unsigned short*)ws; ws += (size_t)B_ * NKV_ * S_ * D_ * 2;
  unsigned short* vtb  = (unsigned short*)ws; ws += (size_t)B_ * NKV_ * S_ * D_ * 2;
  unsigned short* aout = (unsigned short*)ws; ws += (size_t)4096 * 2048 * 2;

  convert_all<<<(int)((CVT_TOTAL + 255) / 256), 256, 0, stream>>>(
      hs, Wq, Wk, Wv, Wg, Wo, Xb, Wall, Wob);
  gemm_bt<true><<<dim3(32, 40), 256, 0, stream>>>(Xb, Wall, (void*)qkvg, 4096, 5120, 2048);
  pack_and_transpose<<<20736, 256, 0, stream>>>(qkvg, cosb, sinb, qw, kw, qb, kbuf, vtb);
  attn_kernel<<<1024, 256, 0, stream>>>(qb, kbuf, vtb, qkvg, aout);
  gemm_bt<false><<<dim3(32, 16), 256, 0, stream>>>(aout, Wob, (void*)out, 4096, 2048, 2048);
}

// Round 2
// 369.271 us; speedup vs baseline: 1.0935x; 1.0655x over previous
//
#include <hip/hip_runtime.h>
#include <hip/hip_bf16.h>

#define B_    2
#define S_    2048
#define H_    2048
#define NH_   16
#define NKV_  4
#define D_    128
#define WIN_  1024

typedef __attribute__((ext_vector_type(8))) short short8;
typedef __attribute__((ext_vector_type(4))) float f32x4;

__device__ __forceinline__ void gl2lds16(const void* g, void* l) {
  __builtin_amdgcn_global_load_lds(
      (const __attribute__((address_space(1))) void*)g,
      (__attribute__((address_space(3))) void*)l, 16, 0, 0);
}

__device__ __forceinline__ unsigned short f2bf(float x) {
  union { float f; unsigned int u; } v; v.f = x;
  unsigned int r = v.u + 0x7fffu + ((v.u >> 16) & 1u);
  return (unsigned short)(r >> 16);
}
__device__ __forceinline__ float bf2f(unsigned short u) {
  union { unsigned int i; float f; } v; v.i = ((unsigned int)u) << 16; return v.f;
}

// ---------------- fused fp32 -> bf16 convert, all 6 tensors in one launch ----
// TOTAL = 5,767,168 float4 chunks = 22,528 blocks x 256.
#define CVT_TOTAL 5767168L
__global__ __launch_bounds__(256) void convert_all(
    const float* __restrict__ hs, const float* __restrict__ wq,
    const float* __restrict__ wk, const float* __restrict__ wv,
    const float* __restrict__ wg, const float* __restrict__ wo,
    unsigned short* __restrict__ xb, unsigned short* __restrict__ wall,
    unsigned short* __restrict__ wob) {
  long i = (long)blockIdx.x * 256 + threadIdx.x;
  if (i >= CVT_TOTAL) return;
  const float4* src; ushort4* dst;
  if (i < 2097152)      { src = (const float4*)hs + i;                         dst = (ushort4*)xb + i; }
  else if (i < 3145728) { long j = i - 2097152; src = (const float4*)wq + j;   dst = (ushort4*)wall + j; }
  else if (i < 3407872) { long j = i - 3145728; src = (const float4*)wk + j;   dst = (ushort4*)wall + 1048576 + j; }
  else if (i < 3670016) { long j = i - 3407872; src = (const float4*)wv + j;   dst = (ushort4*)wall + 1310720 + j; }
  else if (i < 4718592) { long j = i - 3670016; src = (const float4*)wg + j;   dst = (ushort4*)wall + 1572864 + j; }
  else                  { long j = i - 4718592; src = (const float4*)wo + j;   dst = (ushort4*)wob + j; }
  float4 v = *src;
  ushort4 o; o.x = f2bf(v.x); o.y = f2bf(v.y); o.z = f2bf(v.z); o.w = f2bf(v.w);
  *dst = o;
}

// ============ 8-phase 256x320 GEMM for QKVG: C = A(4096x2048) * B(5120x2048)^T
// T2+T3+T4+T5 port of the proven 256^2 8-phase template, adapted to BN=320 so
// grid = 16x16 = 256 blocks = perfect 1 block/CU packing (N=5120 = 16*320).
// 8 waves (2M x 4N), per-wave 128x80 out = 8x5 16x16 frags, BK=64.
// LDS 144KB: As 2x[256][64], Bs 2x[320][64], XOR-chunk swizzle (same verified
// scheme as gemm_bt: physical 16B chunk pc of row r holds logical pc^(r&7)).
// Stage = 9 gl2lds rounds/tile, order B0..B4,A0,A2,A1,A3 issued 3/2/2/2 across
// the previous tile's 4 phases. Counted waits: vmcnt(2) at P3-end (first 7 of
// next tile landed), vmcnt(3) at P0-end (A1,A3 landed; 3 new B in flight).
// Raw s_barrier (NO __syncthreads: that drains vmcnt and kills the pipeline).
#define VMCNT0 asm volatile("s_waitcnt vmcnt(0)" ::: "memory")
#define VMCNT2 asm volatile("s_waitcnt vmcnt(2)" ::: "memory")
#define VMCNT3 asm volatile("s_waitcnt vmcnt(3)" ::: "memory")
#define SBAR   asm volatile("s_barrier" ::: "memory")

__global__ __launch_bounds__(512, 2) void gemm_qkvg(
    const unsigned short* __restrict__ A,   // [4096][2048] bf16
    const unsigned short* __restrict__ Bm,  // [5120][2048] bf16
    unsigned short* __restrict__ C)         // [4096][5120] bf16
{
  const int KQ = 2048, NQ = 5120;
  __shared__ unsigned short As[2][256 * 64];
  __shared__ unsigned short Bs[2][320 * 64];
  const int t = threadIdx.x;
  const int lane = t & 63;
  const int wave = t >> 6;
  const int quad = lane >> 4, rl = lane & 15;
  const int bm = blockIdx.x * 256, bn = blockIdx.y * 320;
  const int wm = (wave >> 2) * 128, wn = (wave & 3) * 80;
  const int wub = (t & ~63) * 8;   // wave-uniform LDS chunk base (shorts)

#define STAGE_A_(d, k0, rd) { int cc = (rd) * 512 + t; int row = cc >> 3;      \
    int lc = (cc & 7) ^ (row & 7);                                             \
    gl2lds16(A + (long)(bm + row) * KQ + (k0) + lc * 8,                        \
             &As[d][(rd) * 4096 + wub]); }
#define STAGE_B_(d, k0, rd) { int cc = (rd) * 512 + t; int row = cc >> 3;      \
    int lc = (cc & 7) ^ (row & 7);                                             \
    gl2lds16(Bm + (long)(bn + row) * KQ + (k0) + lc * 8,                       \
             &Bs[d][(rd) * 4096 + wub]); }
#define RD_B(c, kk) { _Pragma("unroll") for (int j = 0; j < 5; j++) {          \
    int row = wn + j * 16 + rl;                                                \
    bfr[j] = *(const short8*)(&Bs[c][row * 64 + ((((kk)*4+quad)^(row&7))*8)]); } }
#define RD_A(c, kk, f0) { _Pragma("unroll") for (int f = 0; f < 4; f++) {      \
    int row = wm + ((f0) + f) * 16 + rl;                                       \
    af[f] = *(const short8*)(&As[c][row * 64 + ((((kk)*4+quad)^(row&7))*8)]); } }
#define MM(f0) { __builtin_amdgcn_s_setprio(1);                                \
    _Pragma("unroll") for (int f = 0; f < 4; f++)                              \
    _Pragma("unroll") for (int j = 0; j < 5; j++)                              \
      acc[(f0)+f][j] = __builtin_amdgcn_mfma_f32_16x16x32_bf16(                \
          af[f], bfr[j], acc[(f0)+f][j], 0, 0, 0);                             \
    __builtin_amdgcn_s_setprio(0); }

  f32x4 acc[8][5];
#pragma unroll
  for (int f = 0; f < 8; f++)
#pragma unroll
    for (int j = 0; j < 5; j++) acc[f][j] = (f32x4){0.f, 0.f, 0.f, 0.f};

  // prologue: stage tile 0 into buf 0 (canonical order), counted wait
  STAGE_B_(0, 0, 0); STAGE_B_(0, 0, 1); STAGE_B_(0, 0, 2);
  STAGE_B_(0, 0, 3); STAGE_B_(0, 0, 4);
  STAGE_A_(0, 0, 0); STAGE_A_(0, 0, 2);
  STAGE_A_(0, 0, 1); STAGE_A_(0, 0, 3);
  VMCNT2; SBAR;

  for (int tk = 0; tk < 32; ++tk) {
    const int c = tk & 1, d = c ^ 1;
    const int nk0 = tk * 64 + 64;
    const bool hn = tk < 31;
    short8 af[4], bfr[5];
    // ---- P0: B@kk0 + A-half0@kk0 (first-7 of this tile guaranteed landed)
    RD_B(c, 0); RD_A(c, 0, 0);
    if (hn) { STAGE_B_(d, nk0, 0); STAGE_B_(d, nk0, 1); STAGE_B_(d, nk0, 2); }
    SBAR;
    MM(0);
    if (hn) { VMCNT3; } else { VMCNT0; }   // retire this tile's A1,A3
    SBAR;
    // ---- P1: A-half1@kk0
    RD_A(c, 0, 4);
    if (hn) { STAGE_B_(d, nk0, 3); STAGE_B_(d, nk0, 4); }
    SBAR;
    MM(4);
    SBAR;
    // ---- P2: B@kk1 + A-half0@kk1
    RD_B(c, 1); RD_A(c, 1, 0);
    if (hn) { STAGE_A_(d, nk0, 0); STAGE_A_(d, nk0, 2); }
    SBAR;
    MM(0);
    SBAR;
    // ---- P3: A-half1@kk1
    RD_A(c, 1, 4);
    if (hn) { STAGE_A_(d, nk0, 1); STAGE_A_(d, nk0, 3); }
    SBAR;
    MM(4);
    if (hn) { VMCNT2; }                    // next tile's first-7 landed
    SBAR;
  }

  // ---- epilogue: C row = bm+wm+f*16+quad*4+r, col = bn+wn+j*16+rl
#pragma unroll
  for (int f = 0; f < 8; f++) {
    int row0 = bm + wm + f * 16 + quad * 4;
#pragma unroll
    for (int j = 0; j < 5; j++) {
      int col = bn + wn + j * 16 + rl;
#pragma unroll
      for (int r = 0; r < 4; r++)
        C[(long)(row0 + r) * NQ + col] = f2bf(acc[f][j][r]);
    }
  }
#undef STAGE_A_
#undef STAGE_B_
#undef RD_B
#undef RD_A
#undef MM
}

// ---------------- bf16 GEMM: C(MxN) = A(MxK) * B(NxK)^T ----------------
// 128x128 tile, BK=64 (32 K-iters: half the barrier drains of BK=32), 256 thr,
// global_load_lds(16B). Swizzle: physical 16B chunk pc of row r holds logical
// chunk pc^(r&7). Used for the output GEMM (512 blocks = 2 perfect rounds).
template <bool OUT_BF16>
__global__ __launch_bounds__(256) void gemm_bt(
    const unsigned short* __restrict__ A,
    const unsigned short* __restrict__ Bm,
    void* __restrict__ Cv, int M, int N, int K)
{
  __shared__ unsigned short Asl[128 * 64];
  __shared__ unsigned short Bsl[128 * 64];
  const int t = threadIdx.x;
  const int lane = t & 63, wave = t >> 6;
  const int quad = lane >> 4, rl = lane & 15;
  const int bm = blockIdx.x * 128, bn = blockIdx.y * 128;
  const int wm = (wave >> 1) * 64, wn = (wave & 1) * 64;
  const int ldsbase = (t & ~63) * 8;   // wave*512 shorts (1 KiB per wave-instr)

  f32x4 acc[4][4];
#pragma unroll
  for (int i = 0; i < 4; i++)
#pragma unroll
    for (int j = 0; j < 4; j++) acc[i][j] = (f32x4){0.f, 0.f, 0.f, 0.f};

  for (int k0 = 0; k0 < K; k0 += 64) {
#pragma unroll
    for (int i = 0; i < 4; i++) {
      int tt = i * 256 + t;                    // physical 16B-chunk id (0..1023)
      int row = tt >> 3;
      int lc = (tt & 7) ^ (row & 7);           // logical chunk to fetch
      gl2lds16(A + (long)(bm + row) * K + k0 + lc * 8, Asl + i * 2048 + ldsbase);
      gl2lds16(Bm + (long)(bn + row) * K + k0 + lc * 8, Bsl + i * 2048 + ldsbase);
    }
    __syncthreads();
#pragma unroll
    for (int kk = 0; kk < 2; kk++) {
      short8 af[4], bfr[4];
#pragma unroll
      for (int i = 0; i < 4; i++) {
        int row = wm + i * 16 + rl;
        af[i] = *(const short8*)(Asl + row * 64 + (((kk * 4 + quad) ^ (row & 7)) * 8));
      }
#pragma unroll
      for (int j = 0; j < 4; j++) {
        int row = wn + j * 16 + rl;
        bfr[j] = *(const short8*)(Bsl + row * 64 + (((kk * 4 + quad) ^ (row & 7)) * 8));
      }
#pragma unroll
      for (int i = 0; i < 4; i++)
#pragma unroll
        for (int j = 0; j < 4; j++)
          acc[i][j] = __builtin_amdgcn_mfma_f32_16x16x32_bf16(af[i], bfr[j], acc[i][j], 0, 0, 0);
    }
    __syncthreads();
  }
#pragma unroll
  for (int i = 0; i < 4; i++) {
    int row0 = bm + wm + i * 16 + quad * 4;
#pragma unroll
    for (int j = 0; j < 4; j++) {
      int col = bn + wn + j * 16 + rl;
#pragma unroll
      for (int r = 0; r < 4; r++) {
        if (OUT_BF16)
          ((unsigned short*)Cv)[(long)(row0 + r) * N + col] = f2bf(acc[i][j][r]);
        else
          ((float*)Cv)[(long)(row0 + r) * N + col] = acc[i][j][r];
      }
    }
  }
}

// ------- RMSNorm+RoPE pack (blocks 0..20479) + V transpose (blocks 20480+) ---
__global__ __launch_bounds__(256) void pack_and_transpose(
    const unsigned short* __restrict__ qkvg,
    const float* __restrict__ cosb, const float* __restrict__ sinb,
    const float* __restrict__ qw, const float* __restrict__ kw,
    unsigned short* __restrict__ qb, unsigned short* __restrict__ kb,
    unsigned short* __restrict__ vt)
{
  __shared__ unsigned short tile[64][136];
  int t = threadIdx.x;
  if (blockIdx.x >= 20480) {                   // ---- V transpose path ----
    int blk = blockIdx.x - 20480;
    int st = blk & 31, kv = (blk >> 5) & 3, b = blk >> 7;
    int s0 = st * 64;
#pragma unroll
    for (int i = 0; i < 4; i++) {
      int idx = i * 256 + t;
      int r = idx >> 4, c = (idx & 15) * 8;
      short8 v = *(const short8*)(qkvg + (long)(b * S_ + s0 + r) * 5120 + 2560 + kv * 128 + c);
      *(short8*)(&tile[r][c]) = v;
    }
    __syncthreads();
    long vo = (long)(b * NKV_ + kv) * 128;
#pragma unroll
    for (int i = 0; i < 8; i++) {
      int idx = i * 256 + t;
      int d = idx >> 4, sc = idx & 15;
      ushort4 o;
      o.x = tile[sc * 4 + 0][d]; o.y = tile[sc * 4 + 1][d];
      o.z = tile[sc * 4 + 2][d]; o.w = tile[sc * 4 + 3][d];
      *(ushort4*)(vt + (vo + d) * S_ + s0 + sc * 4) = o;
    }
    return;
  }
  // ---- RMSNorm + RoPE path ----
  int lane = t & 63, wave = t >> 6;
  long gw = (long)blockIdx.x * 4 + wave;
  int hu = (int)(gw % 20);
  long bs = gw / 20;
  int b = (int)(bs / S_);
  int s = (int)(bs % S_);
  const unsigned short* row = qkvg + bs * 5120;

  bool isq = hu < 16;
  const unsigned short* base = isq ? (row + hu * 128) : (row + 2048 + (hu - 16) * 128);
  float x1 = bf2f(base[lane]), x2 = bf2f(base[lane + 64]);
  float ss = x1 * x1 + x2 * x2;
#pragma unroll
  for (int m = 1; m < 64; m <<= 1) ss += __shfl_xor(ss, m, 64);
  float inv = rsqrtf(ss * (1.0f / 128.0f) + 1e-5f);
  const float* w = isq ? qw : kw;
  float n1 = x1 * inv * w[lane], n2 = x2 * inv * w[lane + 64];
  const float* cp = cosb + bs * 128;
  const float* sp = sinb + bs * 128;
  float o1 = n1 * cp[lane] - n2 * sp[lane];
  float o2 = n2 * cp[lane + 64] + n1 * sp[lane + 64];
  if (isq) {
    long o = ((long)(b * NH_ + hu) * S_ + s) * 128;
    qb[o + lane] = f2bf(o1); qb[o + lane + 64] = f2bf(o2);
  } else {
    long o = ((long)(b * NKV_ + (hu - 16)) * S_ + s) * 128;
    kb[o + lane] = f2bf(o1); kb[o + lane + 64] = f2bf(o2);
  }
}

// ---------------- flash attention: 1024 blocks x 4 waves, GQA-shared K/V -----
// Block = (qt-desc, b, kv, quarter): 4 waves = 4 heads, each wave does 16 q
// rows (1 mtile). LDS 44.5KB -> 3 blocks/CU resident.
// T13 defer-rescale: skip alpha pass when no row max grows (wave-uniform).
#define KSTR 136   // 128 + 8 shorts
#define VSTR 72    // 64 + 8 shorts
#define PSTR 68    // 64 + 4 shorts
__global__ __launch_bounds__(256, 3) void attn_kernel(
    const unsigned short* __restrict__ qb,   // [B,NH,S,D]
    const unsigned short* __restrict__ kbuf, // [B,NKV,S,D]
    const unsigned short* __restrict__ vt,   // [B,NKV,D,S]
    const unsigned short* __restrict__ qkvg, // gate at col 3072+
    unsigned short* __restrict__ aout)       // [B,S,NH*D] bf16
{
  __shared__ unsigned short Ks[64 * KSTR];      // (key, d) padded
  __shared__ unsigned short Vs[128 * VSTR];     // (d, key) padded
  __shared__ unsigned short Ps[4][16 * PSTR];   // per-wave P (16 rows x 64)
  int t = threadIdx.x, lane = t & 63, wave = t >> 6;
  int quad = lane >> 4, rl = lane & 15;
  int blk = blockIdx.x;
  int qt = 31 - (blk >> 5);                  // heavy blocks dispatch first
  int qu = blk & 3;
  int kv = (blk >> 2) & 3;
  int b  = (blk >> 4) & 1;
  int h = kv * 4 + wave;
  int q0 = qt * 64 + qu * 16;

  const unsigned short* qhead = qb + (((long)(b * NH_ + h)) * S_) * 128;
  short8 qf[4];
#pragma unroll
  for (int ks = 0; ks < 4; ks++)
    qf[ks] = *(const short8*)(qhead + (long)(q0 + rl) * 128 + ks * 32 + quad * 8);

  f32x4 oacc[8];
#pragma unroll
  for (int j = 0; j < 8; j++) oacc[j] = (f32x4){0.f, 0.f, 0.f, 0.f};
  float m_r[4], l_r[4];
#pragma unroll
  for (int r = 0; r < 4; r++) { m_r[r] = -1e9f; l_r[r] = 0.f; }

  const unsigned short* kbase_p = kbuf + ((long)(b * NKV_ + kv)) * S_ * 128;
  const unsigned short* vbase_p = vt + ((long)(b * NKV_ + kv)) * 128 * S_;
  int t_lo = qt - 16; if (t_lo < 0) t_lo = 0;

  // staging indices: K = 64x16 chunks, V = 128x8 chunks; 1024 each / 256 thr
  int kr[4], kc[4], vr[4], vc[4];
#pragma unroll
  for (int i = 0; i < 4; i++) {
    int idx = i * 256 + t;
    kr[i] = idx >> 4; kc[i] = (idx & 15) * 8;
    vr[i] = idx >> 3; vc[i] = (idx & 7) * 8;
  }

  {
    int kb0 = t_lo * 64;
    short8 kv0[4], vv0[4];
#pragma unroll
    for (int i = 0; i < 4; i++) {
      kv0[i] = *(const short8*)(kbase_p + (long)(kb0 + kr[i]) * 128 + kc[i]);
      vv0[i] = *(const short8*)(vbase_p + (long)vr[i] * S_ + kb0 + vc[i]);
    }
#pragma unroll
    for (int i = 0; i < 4; i++) {
      *(short8*)(Ks + kr[i] * KSTR + kc[i]) = kv0[i];
      *(short8*)(Vs + vr[i] * VSTR + vc[i]) = vv0[i];
    }
  }
  __syncthreads();

  const float scale = 0.08838834764831845f;  // 1/sqrt(128)
  for (int kt = t_lo; kt <= qt; ++kt) {
    int kb0 = kt * 64;
    short8 kpre[4], vpre[4];
    if (kt < qt) {
      int nb0 = kb0 + 64;
#pragma unroll
      for (int i = 0; i < 4; i++) {
        kpre[i] = *(const short8*)(kbase_p + (long)(nb0 + kr[i]) * 128 + kc[i]);
        vpre[i] = *(const short8*)(vbase_p + (long)vr[i] * S_ + nb0 + vc[i]);
      }
    }

    f32x4 sc[4];
    __builtin_amdgcn_s_setprio(1);
#pragma unroll
    for (int nt = 0; nt < 4; nt++) {
      f32x4 c0 = (f32x4){0.f, 0.f, 0.f, 0.f};
#pragma unroll
      for (int ks = 0; ks < 4; ks++) {
        short8 bfrag = *(const short8*)(Ks + (nt * 16 + rl) * KSTR + (ks * 4 + quad) * 8);
        c0 = __builtin_amdgcn_mfma_f32_16x16x32_bf16(qf[ks], bfrag, c0, 0, 0, 0);
      }
      sc[nt] = c0;
    }
    __builtin_amdgcn_s_setprio(0);

#pragma unroll
    for (int nt = 0; nt < 4; nt++)
#pragma unroll
      for (int r = 0; r < 4; r++) {
        int i_row = q0 + quad * 4 + r;
        int j_col = kb0 + nt * 16 + rl;
        bool ok = (j_col <= i_row) && (i_row - j_col < WIN_);
        sc[nt][r] = ok ? sc[nt][r] * scale : -1e9f;
      }

    float mx[4];
#pragma unroll
    for (int r = 0; r < 4; r++) {
      float m0 = fmaxf(fmaxf(sc[0][r], sc[1][r]), fmaxf(sc[2][r], sc[3][r]));
#pragma unroll
      for (int m = 1; m < 16; m <<= 1) m0 = fmaxf(m0, __shfl_xor(m0, m, 64));
      mx[r] = m0;
    }
    // T13 defer-rescale: only pay the alpha pass when some row max grew.
    bool need = (mx[0] > m_r[0]) | (mx[1] > m_r[1]) |
                (mx[2] > m_r[2]) | (mx[3] > m_r[3]);
    if (__any(need)) {
#pragma unroll
      for (int r = 0; r < 4; r++) {
        float newm = fmaxf(m_r[r], mx[r]);
        float alpha = __expf(m_r[r] - newm);
        l_r[r] *= alpha;
#pragma unroll
        for (int j = 0; j < 8; j++) oacc[j][r] *= alpha;
        m_r[r] = newm;
      }
    }
#pragma unroll
    for (int r = 0; r < 4; r++) {
      float p0 = __expf(sc[0][r] - m_r[r]), p1 = __expf(sc[1][r] - m_r[r]);
      float p2 = __expf(sc[2][r] - m_r[r]), p3 = __expf(sc[3][r] - m_r[r]);
      float rs = p0 + p1 + p2 + p3;
#pragma unroll
      for (int m = 1; m < 16; m <<= 1) rs += __shfl_xor(rs, m, 64);
      l_r[r] += rs;
      unsigned short* pw = &Ps[wave][(quad * 4 + r) * PSTR];
      pw[0 * 16 + rl] = f2bf(p0);
      pw[1 * 16 + rl] = f2bf(p1);
      pw[2 * 16 + rl] = f2bf(p2);
      pw[3 * 16 + rl] = f2bf(p3);
    }

    __builtin_amdgcn_s_setprio(1);
#pragma unroll
    for (int ks2 = 0; ks2 < 2; ks2++) {
      short8 af = *(const short8*)(&Ps[wave][rl * PSTR + (ks2 * 4 + quad) * 8]);
#pragma unroll
      for (int j = 0; j < 8; j++) {
        short8 bf2 = *(const short8*)(Vs + (j * 16 + rl) * VSTR + (ks2 * 4 + quad) * 8);
        oacc[j] = __builtin_amdgcn_mfma_f32_16x16x32_bf16(af, bf2, oacc[j], 0, 0, 0);
      }
    }
    __builtin_amdgcn_s_setprio(0);

    if (kt < qt) {
      __syncthreads();
#pragma unroll
      for (int i = 0; i < 4; i++) {
        *(short8*)(Ks + kr[i] * KSTR + kc[i]) = kpre[i];
        *(short8*)(Vs + vr[i] * VSTR + vc[i]) = vpre[i];
      }
      __syncthreads();
    }
  }

#pragma unroll
  for (int r = 0; r < 4; r++) {
    int s_idx = q0 + quad * 4 + r;
    float invl = 1.0f / l_r[r];
    long rowoff = (long)(b * S_ + s_idx);
    const unsigned short* gptr = qkvg + rowoff * 5120 + 3072 + h * 128;
    unsigned short* orow = aout + rowoff * 2048 + h * 128;
#pragma unroll
    for (int j = 0; j < 8; j++) {
      int d = j * 16 + rl;
      float o = oacc[j][r] * invl;
      float g = bf2f(gptr[d]);
      o = o / (1.0f + __expf(-g));
      orow[d] = f2bf(o);
    }
  }
}

extern "C" void kernel_launch(void* const* d_in, const int* in_sizes, int n_in,
                              void* d_out, int out_size, void* d_ws, size_t ws_size,
                              hipStream_t stream) {
  (void)in_sizes; (void)n_in; (void)out_size; (void)ws_size;
  const float* hs   = (const float*)d_in[0];
  const float* cosb = (const float*)d_in[1];
  const float* sinb = (const float*)d_in[2];
  const float* Wq = (const float*)d_in[4];
  const float* Wk = (const float*)d_in[5];
  const float* Wv = (const float*)d_in[6];
  const float* Wo = (const float*)d_in[7];
  const float* Wg = (const float*)d_in[8];
  const float* qw = (const float*)d_in[9];
  const float* kw = (const float*)d_in[10];
  float* out = (float*)d_out;

  char* ws = (char*)d_ws;
  unsigned short* Xb   = (unsigned short*)ws; ws += (size_t)4096 * 2048 * 2;
  unsigned short* Wall = (unsigned short*)ws; ws += (size_t)5120 * 2048 * 2;
  unsigned short* Wob  = (unsigned short*)ws; ws += (size_t)2048 * 2048 * 2;
  unsigned short* qkvg = (unsigned short*)ws; ws += (size_t)4096 * 5120 * 2;
  unsigned short* qb   = (unsigned short*)ws; ws += (size_t)B_ * NH_ * S_ * D_ * 2;
  unsigned short* kbuf = (unsigned short*)ws; ws += (size_t)B_ * NKV_ * S_ * D_ * 2;
  unsigned short* vtb  = (unsigned short*)ws; ws += (size_t)B_ * NKV_ * S_ * D_ * 2;
  unsigned short* aout = (unsigned short*)ws; ws += (size_t)4096 * 2048 * 2;

  convert_all<<<(int)((CVT_TOTAL + 255) / 256), 256, 0, stream>>>(
      hs, Wq, Wk, Wv, Wg, Wo, Xb, Wall, Wob);
  gemm_qkvg<<<dim3(16, 16), 512, 0, stream>>>(Xb, Wall, qkvg);
  pack_and_transpose<<<20736, 256, 0, stream>>>(qkvg, cosb, sinb, qw, kw, qb, kbuf, vtb);
  attn_kernel<<<1024, 256, 0, stream>>>(qb, kbuf, vtb, qkvg, aout);
  gemm_bt<false><<<dim3(32, 16), 256, 0, stream>>>(aout, Wob, (void*)out, 4096, 2048, 2048);
}